// Round 1
// baseline (157.262 us; speedup 1.0000x reference)
//
#include <hip/hip_runtime.h>
#include <hip/hip_bf16.h>

#define WDIM 512
#define CHN  512
#define NB   32
#define SZ   64
#define MTOT 4096   // SZ*SZ

typedef __attribute__((ext_vector_type(4))) float f32x4;
typedef __attribute__((ext_vector_type(8))) short short8;
typedef __attribute__((ext_vector_type(4))) int   int4v;
typedef __attribute__((ext_vector_type(4))) float float4v;

// ---------------- setup: per-batch affine+norm, per-(n,c) params ----------------
__global__ __launch_bounds__(512) void setup_kernel(
    const float* __restrict__ w,
    const float* __restrict__ affine_w,
    const float* __restrict__ affine_b,
    const float* __restrict__ freqs,
    const float* __restrict__ phases,
    float* __restrict__ frx_o, float* __restrict__ fry_o,
    float* __restrict__ pha_o, float* __restrict__ amp_o)
{
    const int n = blockIdx.x;
    const int tid = threadIdx.x;
    __shared__ float red[8][4];
    __shared__ float par[4];

    float wv = w[n * WDIM + tid];
    float p0 = wv * affine_w[0 * WDIM + tid];
    float p1 = wv * affine_w[1 * WDIM + tid];
    float p2 = wv * affine_w[2 * WDIM + tid];
    float p3 = wv * affine_w[3 * WDIM + tid];
    #pragma unroll
    for (int off = 32; off >= 1; off >>= 1) {
        p0 += __shfl_down(p0, off);
        p1 += __shfl_down(p1, off);
        p2 += __shfl_down(p2, off);
        p3 += __shfl_down(p3, off);
    }
    const int wave = tid >> 6;
    if ((tid & 63) == 0) {
        red[wave][0] = p0; red[wave][1] = p1;
        red[wave][2] = p2; red[wave][3] = p3;
    }
    __syncthreads();
    if (tid == 0) {
        const float gain = 0.04419417382415922f; // 1/sqrt(512)
        float t[4];
        #pragma unroll
        for (int j = 0; j < 4; ++j) {
            float s = 0.0f;
            #pragma unroll
            for (int v = 0; v < 8; ++v) s += red[v][j];
            t[j] = s * gain + affine_b[j];
        }
        float inv = 1.0f / sqrtf(t[0] * t[0] + t[1] * t[1]);
        float c = t[0] * inv, s = t[1] * inv, tx = t[2] * inv, ty = t[3] * inv;
        par[0] = c;
        par[1] = s;
        par[2] = -c * tx + s * ty;
        par[3] = -s * tx - c * ty;
    }
    __syncthreads();
    const float c_ = par[0], s_ = par[1], tr0 = par[2], tr1 = par[3];
    const int ci = tid; // CH == 512 == blockDim
    float fx = freqs[ci * 2 + 0], fy = freqs[ci * 2 + 1];
    float frx = fx * c_ + fy * s_;
    float fry = -fx * s_ + fy * c_;
    float ph = phases[ci] + fx * tr0 + fy * tr1;
    float r = sqrtf(frx * frx + fry * fry);
    float amp = 1.0f - (r - 2.0f) * (1.0f / 30.0f); // (r-BW)/(SR/2-BW)
    amp = fminf(fmaxf(amp, 0.0f), 1.0f);
    frx_o[n * CHN + ci] = frx;
    fry_o[n * CHN + ci] = fry;
    pha_o[n * CHN + ci] = ph;
    amp_o[n * CHN + ci] = amp;
}

// ---------------- weight -> bf16 * (1/sqrt(CH)) ----------------
__global__ __launch_bounds__(256) void wconv_kernel(
    const float* __restrict__ wsrc, __hip_bfloat16* __restrict__ wbf)
{
    int i = blockIdx.x * 256 + threadIdx.x;
    wbf[i] = __float2bfloat16(wsrc[i] * 0.04419417382415922f);
}

// ---------------- fused features + GEMM ----------------
// out[n,k,hw] = sum_c  sin(2pi*(xs[w]*frx + ys[h]*fry + ph)) * amp * W'[k,c]
// Block: 128 (hw) x 128 (k) tile, BK=64, 4 waves (2x2 of 64x64), 16x16x32 bf16 MFMA.
// Weight frag is the A operand, feature frag is B => D col (lane&15) = hw (coalesced stores).
__global__ __launch_bounds__(256) void fused_kernel(
    const float* __restrict__ frx, const float* __restrict__ fry,
    const float* __restrict__ pha, const float* __restrict__ amp,
    const __hip_bfloat16* __restrict__ wbf,
    float* __restrict__ out)
{
    __shared__ __align__(16) __hip_bfloat16 As[128 * 64]; // features [m][c]
    __shared__ __align__(16) __hip_bfloat16 Bs[128 * 64]; // weight   [k][c]
    __shared__ __align__(16) float Pf[512];
    __shared__ __align__(16) float Pg[512];
    __shared__ __align__(16) float Pp[512];
    __shared__ __align__(16) float Pa[512];

    const int tid = threadIdx.x;
    const int mb = blockIdx.x * 128;
    const int kb = blockIdx.y * 128;
    const int n  = blockIdx.z;

    // stage per-(n,c) params for the whole K range once
    #pragma unroll
    for (int u = 0; u < 2; ++u) {
        int c = tid + u * 256;
        Pf[c] = frx[n * CHN + c];
        Pg[c] = fry[n * CHN + c];
        Pp[c] = pha[n * CHN + c];
        Pa[c] = amp[n * CHN + c];
    }

    const int lane = tid & 63;
    const int wid  = tid >> 6;
    const int ln15 = lane & 15;
    const int hi4  = lane >> 4;
    const int wk = (wid >> 1) * 64; // k-dim wave offset
    const int wm = (wid & 1) * 64;  // m-dim wave offset

    // feature-generation mapping: thread covers rows rb+32i, c-chunk cc0..cc0+7
    const int cc0 = (tid & 7) * 8;
    const int rb  = tid >> 3; // 0..31

    float xsw[4], ysh[4];
    #pragma unroll
    for (int i = 0; i < 4; ++i) {
        int m = mb + rb + i * 32;
        xsw[i] = ((float)(2 * (m & 63) + 1) * (1.0f / 64.0f) - 1.0f) * 0.5f;
        ysh[i] = ((float)(2 * (m >> 6) + 1) * (1.0f / 64.0f) - 1.0f) * 0.5f;
    }

    f32x4 acc[4][4];
    #pragma unroll
    for (int a = 0; a < 4; ++a)
        #pragma unroll
        for (int b = 0; b < 4; ++b)
            acc[a][b] = (f32x4)0.0f;

    for (int kc = 0; kc < 8; ++kc) {
        const int c0 = kc * 64;
        __syncthreads(); // prev MFMA reads done (and param staging on kc==0)

        // stage weight tile Bs[128][64]
        #pragma unroll
        for (int u = 0; u < 4; ++u) {
            int unit = tid + u * 256;       // 0..1023 16B-units
            int row = unit >> 3;            // 0..127
            int cc  = (unit & 7) * 8;       // 0..56
            int4v v = *(const int4v*)&wbf[(size_t)(kb + row) * CHN + c0 + cc];
            *(int4v*)&Bs[row * 64 + cc] = v;
        }

        // compute feature tile As[128][64]
        float4v fx0 = *(const float4v*)&Pf[c0 + cc0], fx1 = *(const float4v*)&Pf[c0 + cc0 + 4];
        float4v fy0 = *(const float4v*)&Pg[c0 + cc0], fy1 = *(const float4v*)&Pg[c0 + cc0 + 4];
        float4v pp0 = *(const float4v*)&Pp[c0 + cc0], pp1 = *(const float4v*)&Pp[c0 + cc0 + 4];
        float4v aa0 = *(const float4v*)&Pa[c0 + cc0], aa1 = *(const float4v*)&Pa[c0 + cc0 + 4];
        #pragma unroll
        for (int i = 0; i < 4; ++i) {
            int r = rb + i * 32;
            union { __hip_bfloat16 h[8]; int4v v; } t;
            #pragma unroll
            for (int j = 0; j < 4; ++j) {
                float arg = xsw[i] * fx0[j] + ysh[i] * fy0[j] + pp0[j];
                t.h[j] = __float2bfloat16(__builtin_amdgcn_sinf(arg) * aa0[j]);
            }
            #pragma unroll
            for (int j = 0; j < 4; ++j) {
                float arg = xsw[i] * fx1[j] + ysh[i] * fy1[j] + pp1[j];
                t.h[4 + j] = __float2bfloat16(__builtin_amdgcn_sinf(arg) * aa1[j]);
            }
            *(int4v*)&As[r * 64 + cc0] = t.v;
        }
        __syncthreads(); // tiles visible

        // MFMA: acc[ki][mj] += W[k,c] x X^T[c,m]
        #pragma unroll
        for (int kk = 0; kk < 2; ++kk) {
            short8 wf[4], ff[4];
            #pragma unroll
            for (int ki = 0; ki < 4; ++ki)
                wf[ki] = *(const short8*)&Bs[(wk + ki * 16 + ln15) * 64 + kk * 32 + hi4 * 8];
            #pragma unroll
            for (int mj = 0; mj < 4; ++mj)
                ff[mj] = *(const short8*)&As[(wm + mj * 16 + ln15) * 64 + kk * 32 + hi4 * 8];
            #pragma unroll
            for (int ki = 0; ki < 4; ++ki)
                #pragma unroll
                for (int mj = 0; mj < 4; ++mj)
                    acc[ki][mj] = __builtin_amdgcn_mfma_f32_16x16x32_bf16(
                        wf[ki], ff[mj], acc[ki][mj], 0, 0, 0);
        }
    }

    // epilogue: out[n][k][hw], col dim of D is hw -> coalesced
    #pragma unroll
    for (int ki = 0; ki < 4; ++ki) {
        #pragma unroll
        for (int mj = 0; mj < 4; ++mj) {
            int kg = kb + wk + ki * 16 + hi4 * 4;
            int mg = mb + wm + mj * 16 + ln15;
            float* op = out + ((size_t)n * CHN + kg) * MTOT + mg;
            #pragma unroll
            for (int rix = 0; rix < 4; ++rix)
                op[(size_t)rix * MTOT] = acc[ki][mj][rix];
        }
    }
}

extern "C" void kernel_launch(void* const* d_in, const int* in_sizes, int n_in,
                              void* d_out, int out_size, void* d_ws, size_t ws_size,
                              hipStream_t stream) {
    const float* w        = (const float*)d_in[0];
    const float* affine_w = (const float*)d_in[1];
    const float* affine_b = (const float*)d_in[2];
    const float* weight   = (const float*)d_in[3];
    const float* freqs    = (const float*)d_in[4];
    const float* phases   = (const float*)d_in[5];
    float* out = (float*)d_out;

    char* ws = (char*)d_ws;
    float* frx = (float*)(ws + 0);
    float* fry = (float*)(ws + 65536);
    float* pha = (float*)(ws + 131072);
    float* amp = (float*)(ws + 196608);
    __hip_bfloat16* wbf = (__hip_bfloat16*)(ws + 262144);

    setup_kernel<<<NB, 512, 0, stream>>>(w, affine_w, affine_b, freqs, phases,
                                         frx, fry, pha, amp);
    wconv_kernel<<<(CHN * CHN) / 256, 256, 0, stream>>>(weight, wbf);

    dim3 grid(MTOT / 128, CHN / 128, NB);
    fused_kernel<<<grid, 256, 0, stream>>>(frx, fry, pha, amp, wbf, out);
}